// Round 4
// baseline (734.220 us; speedup 1.0000x reference)
//
#include <hip/hip_runtime.h>
#include <stdint.h>

// SparseMaskHead: sigmoid -> top-k(2500) -> 5x5 dilation -> stable partition by index.
// Round 4: fix new_mask semantics (rank<NPTS, not dilated-true); flatten histogram
// binning (16 binades x 256 mantissa bins) to kill LDS same-address atomic
// serialization in k_hist; fuse scan into k_write.

namespace {
constexpr int H = 400, W = 400, N = H * W;   // 160000
constexpr int B = 128;
constexpr int NANCH = 2500;
constexpr int NPTS = 20000;
constexpr int NBINS = 4096;
constexpr int POOLCAP = 16384;
constexpr int WPR = 13;                      // 32-bit words per row (400 bits)
constexpr int NWORDS = H * WPR;              // 5200 words per batch
constexpr int NBW = (NWORDS + 255) / 256;    // 21 word-blocks per batch

// output offsets in floats (concat: out_idx, query_pos, new_mask, xy_vox_idx, ignore_idx)
constexpr long long O_QPOS  = (long long)B * NPTS;                  //  2,560,000
constexpr long long O_NMASK = O_QPOS + (long long)B * 4 * NPTS * 3; // 33,280,000
constexpr long long O_XY    = O_NMASK + (long long)B * N;           // 53,760,000
constexpr long long O_IGN   = O_XY + (long long)B * NPTS * 2;       // 58,880,000
}

__device__ __forceinline__ uint32_t score_key(float x, float m) {
    // matches jax.nn.sigmoid at the top-k boundary (x>0): 1/(1+exp(-x)); s>=0 -> bits monotone
    float e = expf(-x);
    float s = 1.0f / (1.0f + e);
    s *= m;
    return __float_as_uint(s);
}

__device__ __forceinline__ int key_bin(uint32_t key) {
    // monotone: 16 binades (s in [2^-16, 1)) x 256 mantissa bins; clamped ends.
    int bin = (int)(key >> 15) - 0x6F00;
    bin = bin < 0 ? 0 : bin;
    return bin > 4095 ? 4095 : bin;
}

// ---- pass 1: per-batch 4096-bin histogram, LDS-privatized --------------------------
__global__ void k_hist(const float* __restrict__ pred, const float* __restrict__ pmask,
                       uint32_t* __restrict__ hist) {
    int b = blockIdx.y;
    __shared__ uint32_t lh[NBINS];
    for (int j = threadIdx.x; j < NBINS; j += 256) lh[j] = 0;
    __syncthreads();
    const float* p = pred + (size_t)b * N + blockIdx.x * 20000;
    const float* m = pmask + (size_t)b * N + blockIdx.x * 20000;
    for (int it = 0; it < 20; ++it) {
        int rel = it * 1024 + threadIdx.x * 4;
        if (rel < 20000) {
            float4 pv = *reinterpret_cast<const float4*>(p + rel);
            float4 mv = *reinterpret_cast<const float4*>(m + rel);
            atomicAdd(&lh[key_bin(score_key(pv.x, mv.x))], 1u);
            atomicAdd(&lh[key_bin(score_key(pv.y, mv.y))], 1u);
            atomicAdd(&lh[key_bin(score_key(pv.z, mv.z))], 1u);
            atomicAdd(&lh[key_bin(score_key(pv.w, mv.w))], 1u);
        }
    }
    __syncthreads();
    uint32_t* gh = hist + (size_t)b * NBINS;
    for (int j = threadIdx.x; j < NBINS; j += 256) {
        uint32_t c = lh[j];
        if (c) atomicAdd(&gh[j], c);
    }
}

// ---- pass 2: find threshold bin Tb and residual rank R per batch (LDS-staged) ------
__global__ void k_pick(const uint32_t* __restrict__ hist, int* __restrict__ Tb,
                       int* __restrict__ Rr) {
    int b = blockIdx.x, t = threadIdx.x;
    const uint32_t* h = hist + (size_t)b * NBINS;
    __shared__ uint32_t lh[NBINS];
    __shared__ uint32_t part[256];
    uint32_t s = 0;
    for (int j = 0; j < 16; ++j) {
        uint32_t v = h[t * 16 + j];
        lh[t * 16 + j] = v;
        s += v;
    }
    part[t] = s;
    __syncthreads();
    if (t == 0) {
        int want = NANCH, acc = 0, c;
        int chunk = 255;
        for (; chunk > 0; --chunk) {
            c = (int)part[chunk];
            if (acc + c >= want) break;
            acc += c;
        }
        int bin = chunk * 16 + 15;
        for (; bin > 0; --bin) {
            c = (int)lh[bin];
            if (acc + c >= want) break;
            acc += c;
        }
        Tb[b] = bin;
        Rr[b] = want - acc;   // #elems to take from the ==Tb pool, >= 1
    }
}

// ---- pass 3: definite anchors -> bit words; boundary pool (full key) ---------------
__global__ void k_compact(const float* __restrict__ pred, const float* __restrict__ pmask,
                          const int* __restrict__ Tb, uint32_t* __restrict__ bits,
                          uint64_t* __restrict__ pool, uint32_t* __restrict__ poolCnt) {
    int b = blockIdx.y;
    int w = blockIdx.x * 256 + threadIdx.x;
    if (w >= NWORDS) return;
    int tb = Tb[b];
    int y = w / WPR, k = w - y * WPR;
    int nv = (k == 12) ? 16 : 32;
    int i0 = y * W + k * 32;
    const float* p = pred + (size_t)b * N + i0;
    const float* m = pmask + (size_t)b * N + i0;
    uint32_t word = 0;
    for (int j = 0; j < nv; j += 4) {
        float4 pv = *reinterpret_cast<const float4*>(p + j);
        float4 mv = *reinterpret_cast<const float4*>(m + j);
        float px[4] = {pv.x, pv.y, pv.z, pv.w};
        float mx[4] = {mv.x, mv.y, mv.z, mv.w};
        #pragma unroll
        for (int q = 0; q < 4; ++q) {
            uint32_t key = score_key(px[q], mx[q]);
            int bn = key_bin(key);
            if (bn > tb) {
                word |= (1u << (j + q));
            } else if (bn == tb) {
                uint32_t pos = atomicAdd(&poolCnt[b], 1u);
                if (pos < POOLCAP)
                    pool[(size_t)b * POOLCAP + pos] =
                        ((uint64_t)key << 32) | (uint32_t)(~(uint32_t)(i0 + j + q));
            }
        }
    }
    bits[(size_t)b * NWORDS + w] = word;
}

// ---- pass 4: exact 64-bit radix select of R-th largest pool value ------------------
__global__ void k_pool(const uint64_t* __restrict__ pool, const uint32_t* __restrict__ poolCnt,
                       const int* __restrict__ Rr, uint32_t* __restrict__ bits) {
    int b = blockIdx.x, t = threadIdx.x;
    int n = min((int)poolCnt[b], POOLCAP);
    if (n == 0) return;
    const uint64_t* pl = pool + (size_t)b * POOLCAP;
    __shared__ uint32_t h[256];
    __shared__ uint64_t s_prefix;
    __shared__ int s_R;
    if (t == 0) { s_prefix = 0; s_R = Rr[b]; }
    __syncthreads();
    for (int d = 7; d >= 0; --d) {
        int shf = d * 8;
        h[t] = 0;
        __syncthreads();
        uint64_t pref = s_prefix;
        uint64_t hiMask = (d == 7) ? 0ull : (~0ull << (shf + 8));
        for (int i = t; i < n; i += 256) {
            uint64_t v = pl[i];
            if ((v & hiMask) == pref)
                atomicAdd(&h[(uint32_t)(v >> shf) & 255u], 1u);
        }
        __syncthreads();
        if (t == 0) {
            int R = s_R, acc = 0, bv;
            for (bv = 255; bv > 0; --bv) {
                int c = (int)h[bv];
                if (acc + c >= R) break;
                acc += c;
            }
            s_R = R - acc;
            s_prefix = pref | ((uint64_t)(uint32_t)bv << shf);
        }
        __syncthreads();
    }
    uint64_t vR = s_prefix;   // exact value of R-th largest (values unique via ~idx)
    for (int i = t; i < n; i += 256) {
        uint64_t v = pl[i];
        if (v >= vR) {
            uint32_t idx = ~((uint32_t)(v & 0xFFFFFFFFull));
            int y = idx / W, x = idx - y * W;
            atomicOr(&bits[(size_t)b * NWORDS + y * WPR + (x >> 5)], 1u << (x & 31));
        }
    }
}

// ---- pass 5: fused 5x5 dilation on bit words + raw block popc sums -----------------
__global__ void k_dil(const uint32_t* __restrict__ src, uint32_t* __restrict__ dst,
                      int* __restrict__ bsum) {
    int b = blockIdx.y, t = threadIdx.x;
    int w = blockIdx.x * 256 + t;
    uint32_t acc = 0;
    if (w < NWORDS) {
        int y = w / WPR, k = w - y * WPR;
        const uint32_t* s = src + (size_t)b * NWORDS;
        int y0 = max(y - 2, 0), y1 = min(y + 2, H - 1);
        for (int yy = y0; yy <= y1; ++yy) {
            const uint32_t* row = s + yy * WPR;
            uint32_t c = row[k];
            uint32_t l = (k > 0) ? row[k - 1] : 0u;
            uint32_t r = (k < 12) ? row[k + 1] : 0u;
            acc |= c | (c << 1) | (c << 2) | (c >> 1) | (c >> 2)
                 | (l >> 30) | (l >> 31) | (r << 30) | (r << 31);
        }
        if (k == 12) acc &= 0xFFFFu;   // row has 400 valid bits
        dst[(size_t)b * NWORDS + w] = acc;
    }
    __shared__ int sh[256];
    sh[t] = __popc(acc);
    __syncthreads();
    for (int off = 128; off > 0; off >>= 1) {
        if (t < off) sh[t] += sh[t + off];
        __syncthreads();
    }
    if (t == 0) bsum[b * NBW + blockIdx.x] = sh[0];
}

// ---- pass 6: out_idx / ignore_idx / new_mask, LDS-staged coalesced flush -----------
__global__ void k_write(const uint32_t* __restrict__ bits, const int* __restrict__ bsum,
                        float* __restrict__ out) {
    int b = blockIdx.y, blk = blockIdx.x, t = threadIdx.x;
    int w = blk * 256 + t;
    uint32_t word = 0;
    int nv = 0, i0 = 0;
    if (w < NWORDS) {
        int y = w / WPR, k = w - y * WPR;
        nv = (k == 12) ? 16 : 32;
        i0 = y * W + k * 32;
        word = bits[(size_t)b * NWORDS + w];
    }
    __shared__ int bs[32];
    if (t < NBW) bs[t] = bsum[b * NBW + t];
    int cnt = __popc(word);
    int packed = (nv << 16) | cnt;
    __shared__ int sh[256];
    sh[t] = packed;
    __syncthreads();
    for (int off = 1; off < 256; off <<= 1) {
        int x = sh[t];
        int yv = (t >= off) ? sh[t - off] : 0;
        __syncthreads();
        sh[t] = x + yv;
        __syncthreads();
    }
    int exc = sh[t] - packed;
    int truOff = exc & 0xFFFF;          // trues before me in block
    int pixOff = exc >> 16;             // pixels before me in block
    int total = sh[255];
    int blockTrues = total & 0xFFFF;
    int foff = pixOff - truOff;         // falses before me in block
    int blockPix = total >> 16;

    int trBase = 0, T = 0;              // trues before this block / total trues
    for (int j = 0; j < NBW; ++j) {
        int v = bs[j];
        T += v;
        if (j < blk) trBase += v;
    }

    __shared__ uint32_t seg[8192];      // [0,blockTrues): true idxs; rest: false idxs
    {
        int c = 0, f = 0;
        for (int j = 0; j < nv; ++j) {
            uint32_t i = (uint32_t)(i0 + j);
            if ((word >> j) & 1u) seg[truOff + (c++)] = i;
            else                  seg[blockTrues + foff + (f++)] = i;
        }
    }
    // new_mask: 1 iff orderPos < NPTS (reference scatters out_idx, not dilated mask)
    if (w < NWORDS) {
        float* nm = out + O_NMASK + (size_t)b * N + i0;
        int rk = trBase + truOff;       // global true-rank of my next true pixel
        for (int j = 0; j < nv; j += 4) {
            float4 v;
            float* vv = &v.x;
            #pragma unroll
            for (int q = 0; q < 4; ++q) {
                int i = i0 + j + q;
                int isT = (int)((word >> (j + q)) & 1u);
                int op = isT ? rk : (T + i - rk);
                vv[q] = (op < NPTS) ? 1.0f : 0.0f;
                rk += isT;
            }
            *reinterpret_cast<float4*>(nm + j) = v;
        }
    }
    __syncthreads();
    // coalesced flush of the stable partition
    int w0 = blk * 256;
    int pixBefore = (w0 / WPR) * W + (w0 % WPR) * 32;
    int fBaseG = pixBefore - trBase;    // falses before this block, globally
    float* outIdx = out + (size_t)b * NPTS;
    float* ign    = out + O_IGN + (size_t)b * (N - NPTS);
    for (int j = t; j < blockPix; j += 256) {
        uint32_t i = seg[j];
        int op = (j < blockTrues) ? (trBase + j) : (T + fBaseG + (j - blockTrues));
        if (op < NPTS) outIdx[op] = (float)i;
        else           ign[op - NPTS] = (float)i;
    }
}

// ---- pass 7: query_pos + xy_vox_idx in pure output order ---------------------------
__global__ void k_qx(const float* __restrict__ zs, float* __restrict__ out) {
    int b = blockIdx.y;
    int j = blockIdx.x * 256 + threadIdx.x;      // float4 index
    const float* oi = out + (size_t)b * NPTS;    // out_idx (written by k_write)
    if (j < 10000) {
        // xy_vox_idx: float4 = {y0,x0,y1,x1} for points 2j, 2j+1
        int ia = (int)oi[2 * j], ib = (int)oi[2 * j + 1];
        float4 v;
        v.x = (float)(ia / W); v.y = (float)(ia % W);
        v.z = (float)(ib / W); v.w = (float)(ib % W);
        *reinterpret_cast<float4*>(out + O_XY + (size_t)b * NPTS * 2 + 4 * j) = v;
    } else if (j < 70000) {
        int g0 = (j - 10000) * 4;                // flat float index into [4][NPTS][3]
        float vv[4];
        #pragma unroll
        for (int e = 0; e < 4; ++e) {
            int g = g0 + e;
            int p = g / 60000;
            int r = g - p * 60000;
            int pt = r / 3, c = r - pt * 3;
            int i = (int)oi[pt];
            float val;
            if (c == 0)      val = ((float)(i % W) + 0.5f) / 400.0f;  // gx
            else if (c == 1) val = ((float)(i / W) + 0.5f) / 400.0f;  // gy
            else             val = zs[p];
            vv[e] = val;
        }
        *reinterpret_cast<float4*>(out + O_QPOS + (size_t)b * 240000 + g0) =
            make_float4(vv[0], vv[1], vv[2], vv[3]);
    }
}

extern "C" void kernel_launch(void* const* d_in, const int* in_sizes, int n_in,
                              void* d_out, int out_size, void* d_ws, size_t ws_size,
                              hipStream_t stream) {
    const float* pred  = (const float*)d_in[0];
    const float* pmask = (const float*)d_in[1];
    const float* zs    = (const float*)d_in[3];
    float* out = (float*)d_out;

    char* ws = (char*)d_ws;
    uint32_t* hist    = (uint32_t*)ws;                          //  2,097,152 B
    uint64_t* pool    = (uint64_t*)(ws + 2097152);              // 16,777,216 B
    uint32_t* abits   = (uint32_t*)(ws + 18874368);             //  2,662,400 B
    uint32_t* dbits   = (uint32_t*)(ws + 21536768);             //  2,662,400 B
    int*      bsum    = (int*)(ws + 24199168);                  //     10,752 B
    int*      Tb      = (int*)(ws + 24209920);
    int*      Rr      = (int*)(ws + 24210432);
    uint32_t* poolCnt = (uint32_t*)(ws + 24210944);

    hipMemsetAsync(hist, 0, (size_t)B * NBINS * 4, stream);
    hipMemsetAsync(poolCnt, 0, (size_t)B * 4, stream);

    k_hist<<<dim3(8, B), 256, 0, stream>>>(pred, pmask, hist);
    k_pick<<<B, 256, 0, stream>>>(hist, Tb, Rr);
    dim3 gw(NBW, B);   // 21 x 128
    k_compact<<<gw, 256, 0, stream>>>(pred, pmask, Tb, abits, pool, poolCnt);
    k_pool<<<B, 256, 0, stream>>>(pool, poolCnt, Rr, abits);
    k_dil<<<gw, 256, 0, stream>>>(abits, dbits, bsum);
    k_write<<<gw, 256, 0, stream>>>(dbits, bsum, out);
    k_qx<<<dim3(274, B), 256, 0, stream>>>(zs, out);
}

// Round 5
// 649.089 us; speedup vs baseline: 1.1312x; 1.1312x over previous
//
#include <hip/hip_runtime.h>
#include <stdint.h>

// SparseMaskHead: sigmoid -> top-k(2500) -> 5x5 dilation -> stable partition by index.
// Round 5: kill latency-bound serial sections (k_pool/k_pick digit picks -> parallel
// suffix-scan), drop both memsets (partial hists + poolCnt zeroed in k_pick),
// thread-per-point k_qx, XOR-swizzled seg[] in k_write.

namespace {
constexpr int H = 400, W = 400, N = H * W;   // 160000
constexpr int B = 128;
constexpr int NANCH = 2500;
constexpr int NPTS = 20000;
constexpr int NBINS = 4096;
constexpr int HBLK = 8;                      // histogram blocks per batch
constexpr int POOLCAP = 16384;
constexpr int WPR = 13;                      // 32-bit words per row (400 bits)
constexpr int NWORDS = H * WPR;              // 5200 words per batch
constexpr int NBW = (NWORDS + 255) / 256;    // 21 word-blocks per batch

// output offsets in floats (concat: out_idx, query_pos, new_mask, xy_vox_idx, ignore_idx)
constexpr long long O_QPOS  = (long long)B * NPTS;                  //  2,560,000
constexpr long long O_NMASK = O_QPOS + (long long)B * 4 * NPTS * 3; // 33,280,000
constexpr long long O_XY    = O_NMASK + (long long)B * N;           // 53,760,000
constexpr long long O_IGN   = O_XY + (long long)B * NPTS * 2;       // 58,880,000
}

#define SW(j) ((j) ^ (((j) >> 5) & 31))      // LDS bank swizzle for seg[]

__device__ __forceinline__ uint32_t score_key(float x, float m) {
    // matches jax.nn.sigmoid at the top-k boundary (x>0): 1/(1+exp(-x)); s>=0 -> bits monotone
    float e = expf(-x);
    float s = 1.0f / (1.0f + e);
    s *= m;
    return __float_as_uint(s);
}

__device__ __forceinline__ int key_bin(uint32_t key) {
    // monotone: 16 binades (s in [2^-16, 1)) x 256 mantissa bins; clamped ends.
    int bin = (int)(key >> 15) - 0x6F00;
    bin = bin < 0 ? 0 : bin;
    return bin > 4095 ? 4095 : bin;
}

// ---- pass 1: per-(batch,block) 4096-bin partial histogram, plain stores ------------
__global__ void k_hist(const float* __restrict__ pred, const float* __restrict__ pmask,
                       uint32_t* __restrict__ hist8) {
    int b = blockIdx.y;
    __shared__ uint32_t lh[NBINS];
    for (int j = threadIdx.x; j < NBINS; j += 256) lh[j] = 0;
    __syncthreads();
    const float* p = pred + (size_t)b * N + blockIdx.x * 20000;
    const float* m = pmask + (size_t)b * N + blockIdx.x * 20000;
    for (int it = 0; it < 20; ++it) {
        int rel = it * 1024 + threadIdx.x * 4;
        if (rel < 20000) {
            float4 pv = *reinterpret_cast<const float4*>(p + rel);
            float4 mv = *reinterpret_cast<const float4*>(m + rel);
            atomicAdd(&lh[key_bin(score_key(pv.x, mv.x))], 1u);
            atomicAdd(&lh[key_bin(score_key(pv.y, mv.y))], 1u);
            atomicAdd(&lh[key_bin(score_key(pv.z, mv.z))], 1u);
            atomicAdd(&lh[key_bin(score_key(pv.w, mv.w))], 1u);
        }
    }
    __syncthreads();
    uint32_t* gh = hist8 + ((size_t)b * HBLK + blockIdx.x) * NBINS;
    for (int j = threadIdx.x; j < NBINS; j += 256) gh[j] = lh[j];
}

// ---- pass 2: threshold bin Tb + residual rank R, parallel suffix-scan pick ---------
__global__ void k_pick(const uint32_t* __restrict__ hist8, int* __restrict__ Tb,
                       int* __restrict__ Rr, uint32_t* __restrict__ poolCnt) {
    int b = blockIdx.x, t = threadIdx.x;
    __shared__ uint32_t lh[NBINS];
    __shared__ uint32_t sc[256];
    __shared__ int s_chunk, s_want2;
    const uint32_t* hb = hist8 + (size_t)b * HBLK * NBINS;
    uint32_t psum = 0;
    for (int jj = 0; jj < 16; ++jj) {
        int j = t * 16 + jj;
        uint32_t s = 0;
        #pragma unroll
        for (int blk = 0; blk < HBLK; ++blk) s += hb[blk * NBINS + j];
        lh[j] = s;
        psum += s;
    }
    sc[255 - t] = psum;                 // reversed for suffix scan
    __syncthreads();
    for (int off = 1; off < 256; off <<= 1) {
        uint32_t x = sc[t];
        uint32_t y = (t >= off) ? sc[t - off] : 0;
        __syncthreads();
        sc[t] = x + y;
        __syncthreads();
    }
    // S(c) = sum over chunks >= c = sc[255-c]
    int want = NANCH;
    uint32_t Sc  = sc[255 - t];
    uint32_t Sc1 = (t == 255) ? 0u : sc[254 - t];
    if ((int)Sc >= want && (int)Sc1 < want) { s_chunk = t; s_want2 = want - (int)Sc1; }
    __syncthreads();
    if (t == 0) {
        int chunk = s_chunk, want2 = s_want2, acc = 0, bin;
        for (bin = chunk * 16 + 15; bin > chunk * 16; --bin) {
            int c = (int)lh[bin];
            if (acc + c >= want2) break;
            acc += c;
        }
        Tb[b] = bin;
        Rr[b] = want2 - acc;            // #elems to take from the ==Tb pool, >= 1
        poolCnt[b] = 0;                 // zero for k_compact (no memset dispatch)
    }
}

// ---- pass 3: definite anchors -> bit words; boundary pool (full key) ---------------
__global__ void k_compact(const float* __restrict__ pred, const float* __restrict__ pmask,
                          const int* __restrict__ Tb, uint32_t* __restrict__ bits,
                          uint64_t* __restrict__ pool, uint32_t* __restrict__ poolCnt) {
    int b = blockIdx.y;
    int w = blockIdx.x * 256 + threadIdx.x;
    if (w >= NWORDS) return;
    int tb = Tb[b];
    int y = w / WPR, k = w - y * WPR;
    int nv = (k == 12) ? 16 : 32;
    int i0 = y * W + k * 32;
    const float* p = pred + (size_t)b * N + i0;
    const float* m = pmask + (size_t)b * N + i0;
    uint32_t word = 0;
    for (int j = 0; j < nv; j += 4) {
        float4 pv = *reinterpret_cast<const float4*>(p + j);
        float4 mv = *reinterpret_cast<const float4*>(m + j);
        float px[4] = {pv.x, pv.y, pv.z, pv.w};
        float mx[4] = {mv.x, mv.y, mv.z, mv.w};
        #pragma unroll
        for (int q = 0; q < 4; ++q) {
            uint32_t key = score_key(px[q], mx[q]);
            int bn = key_bin(key);
            if (bn > tb) {
                word |= (1u << (j + q));
            } else if (bn == tb) {
                uint32_t pos = atomicAdd(&poolCnt[b], 1u);
                if (pos < POOLCAP)
                    pool[(size_t)b * POOLCAP + pos] =
                        ((uint64_t)key << 32) | (uint32_t)(~(uint32_t)(i0 + j + q));
            }
        }
    }
    bits[(size_t)b * NWORDS + w] = word;
}

// ---- pass 4: exact radix select, parallel suffix-scan digit pick -------------------
__global__ void k_pool(const uint64_t* __restrict__ pool, const uint32_t* __restrict__ poolCnt,
                       const int* __restrict__ Rr, uint32_t* __restrict__ bits) {
    int b = blockIdx.x, t = threadIdx.x;
    int n = min((int)poolCnt[b], POOLCAP);
    if (n == 0) return;
    const uint64_t* pl = pool + (size_t)b * POOLCAP;
    __shared__ uint32_t h[256];
    __shared__ uint32_t sc[256];
    __shared__ uint64_t s_prefix;
    __shared__ int s_R;
    if (t == 0) { s_prefix = 0; s_R = Rr[b]; }
    __syncthreads();
    for (int d = 7; d >= 0; --d) {
        int shf = d * 8;
        h[t] = 0;
        __syncthreads();                              // B1
        uint64_t pref = s_prefix;
        uint64_t hiMask = (d == 7) ? 0ull : (~0ull << (shf + 8));
        for (int i = t; i < n; i += 256) {
            uint64_t v = pl[i];
            if ((v & hiMask) == pref)
                atomicAdd(&h[(uint32_t)(v >> shf) & 255u], 1u);
        }
        __syncthreads();                              // B2
        sc[255 - t] = h[t];                           // reversed for suffix sums
        __syncthreads();
        for (int off = 1; off < 256; off <<= 1) {
            uint32_t x = sc[t];
            uint32_t y = (t >= off) ? sc[t - off] : 0;
            __syncthreads();
            sc[t] = x + y;
            __syncthreads();
        }
        // S(v) = count of matching entries with digit >= v = sc[255-v]
        uint32_t Sv  = sc[255 - t];
        uint32_t Sv1 = (t == 255) ? 0u : sc[254 - t];
        int R = s_R;
        __syncthreads();                              // B3: all reads of s_R done
        if ((int)Sv >= R && (int)Sv1 < R) {           // exactly one digit wins
            s_R = R - (int)Sv1;
            s_prefix = pref | ((uint64_t)(uint32_t)t << shf);
        }
        __syncthreads();                              // B4
    }
    uint64_t vR = s_prefix;   // exact value of R-th largest (values unique via ~idx)
    for (int i = t; i < n; i += 256) {
        uint64_t v = pl[i];
        if (v >= vR) {
            uint32_t idx = ~((uint32_t)(v & 0xFFFFFFFFull));
            int y = idx / W, x = idx - y * W;
            atomicOr(&bits[(size_t)b * NWORDS + y * WPR + (x >> 5)], 1u << (x & 31));
        }
    }
}

// ---- pass 5: fused 5x5 dilation on bit words + raw block popc sums -----------------
__global__ void k_dil(const uint32_t* __restrict__ src, uint32_t* __restrict__ dst,
                      int* __restrict__ bsum) {
    int b = blockIdx.y, t = threadIdx.x;
    int w = blockIdx.x * 256 + t;
    uint32_t acc = 0;
    if (w < NWORDS) {
        int y = w / WPR, k = w - y * WPR;
        const uint32_t* s = src + (size_t)b * NWORDS;
        int y0 = max(y - 2, 0), y1 = min(y + 2, H - 1);
        for (int yy = y0; yy <= y1; ++yy) {
            const uint32_t* row = s + yy * WPR;
            uint32_t c = row[k];
            uint32_t l = (k > 0) ? row[k - 1] : 0u;
            uint32_t r = (k < 12) ? row[k + 1] : 0u;
            acc |= c | (c << 1) | (c << 2) | (c >> 1) | (c >> 2)
                 | (l >> 30) | (l >> 31) | (r << 30) | (r << 31);
        }
        if (k == 12) acc &= 0xFFFFu;   // row has 400 valid bits
        dst[(size_t)b * NWORDS + w] = acc;
    }
    __shared__ int sh[256];
    sh[t] = __popc(acc);
    __syncthreads();
    for (int off = 128; off > 0; off >>= 1) {
        if (t < off) sh[t] += sh[t + off];
        __syncthreads();
    }
    if (t == 0) bsum[b * NBW + blockIdx.x] = sh[0];
}

// ---- pass 6: out_idx / ignore_idx / new_mask, LDS-staged coalesced flush -----------
__global__ void k_write(const uint32_t* __restrict__ bits, const int* __restrict__ bsum,
                        float* __restrict__ out) {
    int b = blockIdx.y, blk = blockIdx.x, t = threadIdx.x;
    int w = blk * 256 + t;
    uint32_t word = 0;
    int nv = 0, i0 = 0;
    if (w < NWORDS) {
        int y = w / WPR, k = w - y * WPR;
        nv = (k == 12) ? 16 : 32;
        i0 = y * W + k * 32;
        word = bits[(size_t)b * NWORDS + w];
    }
    __shared__ int bs[32];
    if (t < NBW) bs[t] = bsum[b * NBW + t];
    int cnt = __popc(word);
    int packed = (nv << 16) | cnt;
    __shared__ int sh[256];
    sh[t] = packed;
    __syncthreads();
    for (int off = 1; off < 256; off <<= 1) {
        int x = sh[t];
        int yv = (t >= off) ? sh[t - off] : 0;
        __syncthreads();
        sh[t] = x + yv;
        __syncthreads();
    }
    int exc = sh[t] - packed;
    int truOff = exc & 0xFFFF;          // trues before me in block
    int pixOff = exc >> 16;             // pixels before me in block
    int total = sh[255];
    int blockTrues = total & 0xFFFF;
    int foff = pixOff - truOff;         // falses before me in block
    int blockPix = total >> 16;

    int trBase = 0, T = 0;              // trues before this block / total trues
    for (int j = 0; j < NBW; ++j) {
        int v = bs[j];
        T += v;
        if (j < blk) trBase += v;
    }

    __shared__ uint32_t seg[8192];      // [0,blockTrues): true idxs; rest: false idxs
    {
        int c = truOff, f = blockTrues + foff;
        for (int j = 0; j < nv; ++j) {
            uint32_t i = (uint32_t)(i0 + j);
            if ((word >> j) & 1u) seg[SW(c)] = i, ++c;
            else                  seg[SW(f)] = i, ++f;
        }
    }
    // new_mask: 1 iff orderPos < NPTS (reference scatters out_idx, not dilated mask)
    if (w < NWORDS) {
        float* nm = out + O_NMASK + (size_t)b * N + i0;
        int rk = trBase + truOff;       // global true-rank of my next true pixel
        for (int j = 0; j < nv; j += 4) {
            float4 v;
            float* vv = &v.x;
            #pragma unroll
            for (int q = 0; q < 4; ++q) {
                int i = i0 + j + q;
                int isT = (int)((word >> (j + q)) & 1u);
                int op = isT ? rk : (T + i - rk);
                vv[q] = (op < NPTS) ? 1.0f : 0.0f;
                rk += isT;
            }
            *reinterpret_cast<float4*>(nm + j) = v;
        }
    }
    __syncthreads();
    // coalesced flush of the stable partition
    int w0 = blk * 256;
    int pixBefore = (w0 / WPR) * W + (w0 % WPR) * 32;
    int fBaseG = pixBefore - trBase;    // falses before this block, globally
    float* outIdx = out + (size_t)b * NPTS;
    float* ign    = out + O_IGN + (size_t)b * (N - NPTS);
    for (int j = t; j < blockPix; j += 256) {
        uint32_t i = seg[SW(j)];
        int op = (j < blockTrues) ? (trBase + j) : (T + fBaseG + (j - blockTrues));
        if (op < NPTS) outIdx[op] = (float)i;
        else           ign[op - NPTS] = (float)i;
    }
}

// ---- pass 7: query_pos + xy_vox_idx, one thread per point --------------------------
__global__ void k_qx(const float* __restrict__ zs, float* __restrict__ out) {
    int b = blockIdx.y;
    int pt = blockIdx.x * 256 + threadIdx.x;
    if (pt >= NPTS) return;
    int i = (int)out[(size_t)b * NPTS + pt];      // out_idx (written by k_write)
    int y = i / W, x = i - y * W;
    // xy_vox_idx = {i // H, i % W} = {y, x}  (H == W == 400)
    float2 xv;
    xv.x = (float)y; xv.y = (float)x;
    *reinterpret_cast<float2*>(out + O_XY + (size_t)b * NPTS * 2 + 2 * pt) = xv;
    // query_pos: gx=(x+0.5)/400, gy=(y+0.5)/400 exactly match f32 linspace/W values
    float gx = ((float)x + 0.5f) * 0.0025f;
    float gy = ((float)y + 0.5f) * 0.0025f;
    float* q = out + O_QPOS + (size_t)b * 240000 + (size_t)pt * 3;
    #pragma unroll
    for (int p = 0; p < 4; ++p) {
        q[0] = gx; q[1] = gy; q[2] = zs[p];
        q += (size_t)NPTS * 3;
    }
}

extern "C" void kernel_launch(void* const* d_in, const int* in_sizes, int n_in,
                              void* d_out, int out_size, void* d_ws, size_t ws_size,
                              hipStream_t stream) {
    const float* pred  = (const float*)d_in[0];
    const float* pmask = (const float*)d_in[1];
    const float* zs    = (const float*)d_in[3];
    float* out = (float*)d_out;

    char* ws = (char*)d_ws;
    uint32_t* hist8   = (uint32_t*)ws;                          // 16,777,216 B
    uint64_t* pool    = (uint64_t*)(ws + 16777216);             // 16,777,216 B
    uint32_t* abits   = (uint32_t*)(ws + 33554432);             //  2,662,400 B
    uint32_t* dbits   = (uint32_t*)(ws + 36216832);             //  2,662,400 B
    int*      bsum    = (int*)(ws + 38879232);                  //     10,752 B
    int*      Tb      = (int*)(ws + 38890496);
    int*      Rr      = (int*)(ws + 38891008);
    uint32_t* poolCnt = (uint32_t*)(ws + 38891520);

    k_hist<<<dim3(HBLK, B), 256, 0, stream>>>(pred, pmask, hist8);
    k_pick<<<B, 256, 0, stream>>>(hist8, Tb, Rr, poolCnt);
    dim3 gw(NBW, B);   // 21 x 128
    k_compact<<<gw, 256, 0, stream>>>(pred, pmask, Tb, abits, pool, poolCnt);
    k_pool<<<B, 256, 0, stream>>>(pool, poolCnt, Rr, abits);
    k_dil<<<gw, 256, 0, stream>>>(abits, dbits, bsum);
    k_write<<<gw, 256, 0, stream>>>(dbits, bsum, out);
    k_qx<<<dim3(79, B), 256, 0, stream>>>(zs, out);
}

// Round 6
// 647.911 us; speedup vs baseline: 1.1332x; 1.0018x over previous
//
#include <hip/hip_runtime.h>
#include <stdint.h>

// SparseMaskHead: sigmoid -> top-k(2500) -> 5x5 dilation -> stable partition by index.
// Round 6: fuse k_qx into k_write (xy/qpos written coalesced at flush time, one less
// dispatch + no out_idx re-read); HBLK 8->4 halves partial-hist round-trip.

namespace {
constexpr int H = 400, W = 400, N = H * W;   // 160000
constexpr int B = 128;
constexpr int NANCH = 2500;
constexpr int NPTS = 20000;
constexpr int NBINS = 4096;
constexpr int HBLK = 4;                      // histogram blocks per batch
constexpr int ELB = N / HBLK;                // 40000 elements per hist block
constexpr int POOLCAP = 16384;
constexpr int WPR = 13;                      // 32-bit words per row (400 bits)
constexpr int NWORDS = H * WPR;              // 5200 words per batch
constexpr int NBW = (NWORDS + 255) / 256;    // 21 word-blocks per batch

// output offsets in floats (concat: out_idx, query_pos, new_mask, xy_vox_idx, ignore_idx)
constexpr long long O_QPOS  = (long long)B * NPTS;                  //  2,560,000
constexpr long long O_NMASK = O_QPOS + (long long)B * 4 * NPTS * 3; // 33,280,000
constexpr long long O_XY    = O_NMASK + (long long)B * N;           // 53,760,000
constexpr long long O_IGN   = O_XY + (long long)B * NPTS * 2;       // 58,880,000
}

#define SW(j) ((j) ^ (((j) >> 5) & 31))      // LDS bank swizzle for seg[]

__device__ __forceinline__ uint32_t score_key(float x, float m) {
    // matches jax.nn.sigmoid at the top-k boundary (x>0): 1/(1+exp(-x)); s>=0 -> bits monotone
    float e = expf(-x);
    float s = 1.0f / (1.0f + e);
    s *= m;
    return __float_as_uint(s);
}

__device__ __forceinline__ int key_bin(uint32_t key) {
    // monotone: 16 binades (s in [2^-16, 1)) x 256 mantissa bins; clamped ends.
    int bin = (int)(key >> 15) - 0x6F00;
    bin = bin < 0 ? 0 : bin;
    return bin > 4095 ? 4095 : bin;
}

// ---- pass 1: per-(batch,block) 4096-bin partial histogram, plain stores ------------
__global__ void k_hist(const float* __restrict__ pred, const float* __restrict__ pmask,
                       uint32_t* __restrict__ histp) {
    int b = blockIdx.y;
    __shared__ uint32_t lh[NBINS];
    for (int j = threadIdx.x; j < NBINS; j += 256) lh[j] = 0;
    __syncthreads();
    const float* p = pred + (size_t)b * N + blockIdx.x * ELB;
    const float* m = pmask + (size_t)b * N + blockIdx.x * ELB;
    for (int it = 0; it < (ELB + 1023) / 1024; ++it) {
        int rel = it * 1024 + threadIdx.x * 4;
        if (rel < ELB) {
            float4 pv = *reinterpret_cast<const float4*>(p + rel);
            float4 mv = *reinterpret_cast<const float4*>(m + rel);
            atomicAdd(&lh[key_bin(score_key(pv.x, mv.x))], 1u);
            atomicAdd(&lh[key_bin(score_key(pv.y, mv.y))], 1u);
            atomicAdd(&lh[key_bin(score_key(pv.z, mv.z))], 1u);
            atomicAdd(&lh[key_bin(score_key(pv.w, mv.w))], 1u);
        }
    }
    __syncthreads();
    uint32_t* gh = histp + ((size_t)b * HBLK + blockIdx.x) * NBINS;
    for (int j = threadIdx.x; j < NBINS; j += 256) gh[j] = lh[j];
}

// ---- pass 2: threshold bin Tb + residual rank R, parallel suffix-scan pick ---------
__global__ void k_pick(const uint32_t* __restrict__ histp, int* __restrict__ Tb,
                       int* __restrict__ Rr, uint32_t* __restrict__ poolCnt) {
    int b = blockIdx.x, t = threadIdx.x;
    __shared__ uint32_t lh[NBINS];
    __shared__ uint32_t sc[256];
    __shared__ int s_chunk, s_want2;
    const uint32_t* hb = histp + (size_t)b * HBLK * NBINS;
    uint32_t psum = 0;
    for (int jj = 0; jj < 16; ++jj) {
        int j = t * 16 + jj;
        uint32_t s = 0;
        #pragma unroll
        for (int blk = 0; blk < HBLK; ++blk) s += hb[blk * NBINS + j];
        lh[j] = s;
        psum += s;
    }
    sc[255 - t] = psum;                 // reversed for suffix scan
    __syncthreads();
    for (int off = 1; off < 256; off <<= 1) {
        uint32_t x = sc[t];
        uint32_t y = (t >= off) ? sc[t - off] : 0;
        __syncthreads();
        sc[t] = x + y;
        __syncthreads();
    }
    // S(c) = sum over chunks >= c = sc[255-c]
    int want = NANCH;
    uint32_t Sc  = sc[255 - t];
    uint32_t Sc1 = (t == 255) ? 0u : sc[254 - t];
    if ((int)Sc >= want && (int)Sc1 < want) { s_chunk = t; s_want2 = want - (int)Sc1; }
    __syncthreads();
    if (t == 0) {
        int chunk = s_chunk, want2 = s_want2, acc = 0, bin;
        for (bin = chunk * 16 + 15; bin > chunk * 16; --bin) {
            int c = (int)lh[bin];
            if (acc + c >= want2) break;
            acc += c;
        }
        Tb[b] = bin;
        Rr[b] = want2 - acc;            // #elems to take from the ==Tb pool, >= 1
        poolCnt[b] = 0;                 // zero for k_compact (no memset dispatch)
    }
}

// ---- pass 3: definite anchors -> bit words; boundary pool (full key) ---------------
__global__ void k_compact(const float* __restrict__ pred, const float* __restrict__ pmask,
                          const int* __restrict__ Tb, uint32_t* __restrict__ bits,
                          uint64_t* __restrict__ pool, uint32_t* __restrict__ poolCnt) {
    int b = blockIdx.y;
    int w = blockIdx.x * 256 + threadIdx.x;
    if (w >= NWORDS) return;
    int tb = Tb[b];
    int y = w / WPR, k = w - y * WPR;
    int nv = (k == 12) ? 16 : 32;
    int i0 = y * W + k * 32;
    const float* p = pred + (size_t)b * N + i0;
    const float* m = pmask + (size_t)b * N + i0;
    uint32_t word = 0;
    for (int j = 0; j < nv; j += 4) {
        float4 pv = *reinterpret_cast<const float4*>(p + j);
        float4 mv = *reinterpret_cast<const float4*>(m + j);
        float px[4] = {pv.x, pv.y, pv.z, pv.w};
        float mx[4] = {mv.x, mv.y, mv.z, mv.w};
        #pragma unroll
        for (int q = 0; q < 4; ++q) {
            uint32_t key = score_key(px[q], mx[q]);
            int bn = key_bin(key);
            if (bn > tb) {
                word |= (1u << (j + q));
            } else if (bn == tb) {
                uint32_t pos = atomicAdd(&poolCnt[b], 1u);
                if (pos < POOLCAP)
                    pool[(size_t)b * POOLCAP + pos] =
                        ((uint64_t)key << 32) | (uint32_t)(~(uint32_t)(i0 + j + q));
            }
        }
    }
    bits[(size_t)b * NWORDS + w] = word;
}

// ---- pass 4: exact radix select, parallel suffix-scan digit pick -------------------
__global__ void k_pool(const uint64_t* __restrict__ pool, const uint32_t* __restrict__ poolCnt,
                       const int* __restrict__ Rr, uint32_t* __restrict__ bits) {
    int b = blockIdx.x, t = threadIdx.x;
    int n = min((int)poolCnt[b], POOLCAP);
    if (n == 0) return;
    const uint64_t* pl = pool + (size_t)b * POOLCAP;
    __shared__ uint32_t h[256];
    __shared__ uint32_t sc[256];
    __shared__ uint64_t s_prefix;
    __shared__ int s_R;
    if (t == 0) { s_prefix = 0; s_R = Rr[b]; }
    __syncthreads();
    for (int d = 7; d >= 0; --d) {
        int shf = d * 8;
        h[t] = 0;
        __syncthreads();                              // B1
        uint64_t pref = s_prefix;
        uint64_t hiMask = (d == 7) ? 0ull : (~0ull << (shf + 8));
        for (int i = t; i < n; i += 256) {
            uint64_t v = pl[i];
            if ((v & hiMask) == pref)
                atomicAdd(&h[(uint32_t)(v >> shf) & 255u], 1u);
        }
        __syncthreads();                              // B2
        sc[255 - t] = h[t];                           // reversed for suffix sums
        __syncthreads();
        for (int off = 1; off < 256; off <<= 1) {
            uint32_t x = sc[t];
            uint32_t y = (t >= off) ? sc[t - off] : 0;
            __syncthreads();
            sc[t] = x + y;
            __syncthreads();
        }
        // S(v) = count of matching entries with digit >= v = sc[255-v]
        uint32_t Sv  = sc[255 - t];
        uint32_t Sv1 = (t == 255) ? 0u : sc[254 - t];
        int R = s_R;
        __syncthreads();                              // B3: all reads of s_R done
        if ((int)Sv >= R && (int)Sv1 < R) {           // exactly one digit wins
            s_R = R - (int)Sv1;
            s_prefix = pref | ((uint64_t)(uint32_t)t << shf);
        }
        __syncthreads();                              // B4
    }
    uint64_t vR = s_prefix;   // exact value of R-th largest (values unique via ~idx)
    for (int i = t; i < n; i += 256) {
        uint64_t v = pl[i];
        if (v >= vR) {
            uint32_t idx = ~((uint32_t)(v & 0xFFFFFFFFull));
            int y = idx / W, x = idx - y * W;
            atomicOr(&bits[(size_t)b * NWORDS + y * WPR + (x >> 5)], 1u << (x & 31));
        }
    }
}

// ---- pass 5: fused 5x5 dilation on bit words + raw block popc sums -----------------
__global__ void k_dil(const uint32_t* __restrict__ src, uint32_t* __restrict__ dst,
                      int* __restrict__ bsum) {
    int b = blockIdx.y, t = threadIdx.x;
    int w = blockIdx.x * 256 + t;
    uint32_t acc = 0;
    if (w < NWORDS) {
        int y = w / WPR, k = w - y * WPR;
        const uint32_t* s = src + (size_t)b * NWORDS;
        int y0 = max(y - 2, 0), y1 = min(y + 2, H - 1);
        for (int yy = y0; yy <= y1; ++yy) {
            const uint32_t* row = s + yy * WPR;
            uint32_t c = row[k];
            uint32_t l = (k > 0) ? row[k - 1] : 0u;
            uint32_t r = (k < 12) ? row[k + 1] : 0u;
            acc |= c | (c << 1) | (c << 2) | (c >> 1) | (c >> 2)
                 | (l >> 30) | (l >> 31) | (r << 30) | (r << 31);
        }
        if (k == 12) acc &= 0xFFFFu;   // row has 400 valid bits
        dst[(size_t)b * NWORDS + w] = acc;
    }
    __shared__ int sh[256];
    sh[t] = __popc(acc);
    __syncthreads();
    for (int off = 128; off > 0; off >>= 1) {
        if (t < off) sh[t] += sh[t + off];
        __syncthreads();
    }
    if (t == 0) bsum[b * NBW + blockIdx.x] = sh[0];
}

// ---- pass 6: ALL outputs, LDS-staged coalesced flush (qpos/xy fused in) ------------
__global__ void k_write(const uint32_t* __restrict__ bits, const int* __restrict__ bsum,
                        const float* __restrict__ zs, float* __restrict__ out) {
    int b = blockIdx.y, blk = blockIdx.x, t = threadIdx.x;
    int w = blk * 256 + t;
    uint32_t word = 0;
    int nv = 0, i0 = 0;
    if (w < NWORDS) {
        int y = w / WPR, k = w - y * WPR;
        nv = (k == 12) ? 16 : 32;
        i0 = y * W + k * 32;
        word = bits[(size_t)b * NWORDS + w];
    }
    __shared__ int bs[32];
    if (t < NBW) bs[t] = bsum[b * NBW + t];
    int cnt = __popc(word);
    int packed = (nv << 16) | cnt;
    __shared__ int sh[256];
    sh[t] = packed;
    __syncthreads();
    for (int off = 1; off < 256; off <<= 1) {
        int x = sh[t];
        int yv = (t >= off) ? sh[t - off] : 0;
        __syncthreads();
        sh[t] = x + yv;
        __syncthreads();
    }
    int exc = sh[t] - packed;
    int truOff = exc & 0xFFFF;          // trues before me in block
    int pixOff = exc >> 16;             // pixels before me in block
    int total = sh[255];
    int blockTrues = total & 0xFFFF;
    int foff = pixOff - truOff;         // falses before me in block
    int blockPix = total >> 16;

    int trBase = 0, T = 0;              // trues before this block / total trues
    for (int j = 0; j < NBW; ++j) {
        int v = bs[j];
        T += v;
        if (j < blk) trBase += v;
    }

    __shared__ uint32_t seg[8192];      // [0,blockTrues): true idxs; rest: false idxs
    {
        int c = truOff, f = blockTrues + foff;
        for (int j = 0; j < nv; ++j) {
            uint32_t i = (uint32_t)(i0 + j);
            if ((word >> j) & 1u) seg[SW(c)] = i, ++c;
            else                  seg[SW(f)] = i, ++f;
        }
    }
    // new_mask: 1 iff orderPos < NPTS (reference scatters out_idx, not dilated mask)
    if (w < NWORDS) {
        float* nm = out + O_NMASK + (size_t)b * N + i0;
        int rk = trBase + truOff;       // global true-rank of my next true pixel
        for (int j = 0; j < nv; j += 4) {
            float4 v;
            float* vv = &v.x;
            #pragma unroll
            for (int q = 0; q < 4; ++q) {
                int i = i0 + j + q;
                int isT = (int)((word >> (j + q)) & 1u);
                int op = isT ? rk : (T + i - rk);
                vv[q] = (op < NPTS) ? 1.0f : 0.0f;
                rk += isT;
            }
            *reinterpret_cast<float4*>(nm + j) = v;
        }
    }
    __syncthreads();
    // coalesced flush of the stable partition + qpos/xy in the same pass
    int w0 = blk * 256;
    int pixBefore = (w0 / WPR) * W + (w0 % WPR) * 32;
    int fBaseG = pixBefore - trBase;    // falses before this block, globally
    float z0 = zs[0], z1 = zs[1], z2 = zs[2], z3 = zs[3];
    float* outIdx = out + (size_t)b * NPTS;
    float* qpos   = out + O_QPOS + (size_t)b * 240000;
    float* xy     = out + O_XY   + (size_t)b * NPTS * 2;
    float* ign    = out + O_IGN  + (size_t)b * (N - NPTS);
    for (int j = t; j < blockPix; j += 256) {
        uint32_t i = seg[SW(j)];
        int op = (j < blockTrues) ? (trBase + j) : (T + fBaseG + (j - blockTrues));
        if (op < NPTS) {
            outIdx[op] = (float)i;
            int yy = (int)i / W, xx = (int)i - yy * W;
            // xy_vox_idx = {i // H, i % W} = {yy, xx}  (H == W == 400)
            *reinterpret_cast<float2*>(xy + 2 * op) =
                make_float2((float)yy, (float)xx);
            float gx = ((float)xx + 0.5f) * 0.0025f;
            float gy = ((float)yy + 0.5f) * 0.0025f;
            float* q = qpos + (size_t)op * 3;
            q[0] = gx; q[1] = gy; q[2] = z0;
            q += 60000; q[0] = gx; q[1] = gy; q[2] = z1;
            q += 60000; q[0] = gx; q[1] = gy; q[2] = z2;
            q += 60000; q[0] = gx; q[1] = gy; q[2] = z3;
        } else {
            ign[op - NPTS] = (float)i;
        }
    }
}

extern "C" void kernel_launch(void* const* d_in, const int* in_sizes, int n_in,
                              void* d_out, int out_size, void* d_ws, size_t ws_size,
                              hipStream_t stream) {
    const float* pred  = (const float*)d_in[0];
    const float* pmask = (const float*)d_in[1];
    const float* zs    = (const float*)d_in[3];
    float* out = (float*)d_out;

    char* ws = (char*)d_ws;
    uint32_t* histp   = (uint32_t*)ws;                          //  8,388,608 B
    uint64_t* pool    = (uint64_t*)(ws + 8388608);              // 16,777,216 B
    uint32_t* abits   = (uint32_t*)(ws + 25165824);             //  2,662,400 B
    uint32_t* dbits   = (uint32_t*)(ws + 27828224);             //  2,662,400 B
    int*      bsum    = (int*)(ws + 30490624);                  //     10,752 B
    int*      Tb      = (int*)(ws + 30501376);
    int*      Rr      = (int*)(ws + 30501888);
    uint32_t* poolCnt = (uint32_t*)(ws + 30502400);

    k_hist<<<dim3(HBLK, B), 256, 0, stream>>>(pred, pmask, histp);
    k_pick<<<B, 256, 0, stream>>>(histp, Tb, Rr, poolCnt);
    dim3 gw(NBW, B);   // 21 x 128
    k_compact<<<gw, 256, 0, stream>>>(pred, pmask, Tb, abits, pool, poolCnt);
    k_pool<<<B, 256, 0, stream>>>(pool, poolCnt, Rr, abits);
    k_dil<<<gw, 256, 0, stream>>>(abits, dbits, bsum);
    k_write<<<gw, 256, 0, stream>>>(dbits, bsum, zs, out);
}

// Round 7
// 552.190 us; speedup vs baseline: 1.3297x; 1.1733x over previous
//
#include <hip/hip_runtime.h>
#include <stdint.h>

// SparseMaskHead: sigmoid -> top-k(2500) -> 5x5 dilation -> stable partition by index.
// Round 7: single-pass scoring. k_hist caches per-element 12-bit bin (u16 -> ws);
// k_compact reads bins (41MB) instead of re-reading pred+pmask (164MB) and
// re-running expf; full key recomputed only for rare bin==tb boundary elements.

namespace {
constexpr int H = 400, W = 400, N = H * W;   // 160000
constexpr int B = 128;
constexpr int NANCH = 2500;
constexpr int NPTS = 20000;
constexpr int NBINS = 4096;
constexpr int HBLK = 4;                      // histogram blocks per batch
constexpr int ELB = N / HBLK;                // 40000 elements per hist block
constexpr int POOLCAP = 16384;
constexpr int WPR = 13;                      // 32-bit words per row (400 bits)
constexpr int NWORDS = H * WPR;              // 5200 words per batch
constexpr int NBW = (NWORDS + 255) / 256;    // 21 word-blocks per batch

// output offsets in floats (concat: out_idx, query_pos, new_mask, xy_vox_idx, ignore_idx)
constexpr long long O_QPOS  = (long long)B * NPTS;                  //  2,560,000
constexpr long long O_NMASK = O_QPOS + (long long)B * 4 * NPTS * 3; // 33,280,000
constexpr long long O_XY    = O_NMASK + (long long)B * N;           // 53,760,000
constexpr long long O_IGN   = O_XY + (long long)B * NPTS * 2;       // 58,880,000
}

#define SW(j) ((j) ^ (((j) >> 5) & 31))      // LDS bank swizzle for seg[]

__device__ __forceinline__ uint32_t score_key(float x, float m) {
    // matches jax.nn.sigmoid at the top-k boundary (x>0): 1/(1+exp(-x)); s>=0 -> bits monotone
    float e = expf(-x);
    float s = 1.0f / (1.0f + e);
    s *= m;
    return __float_as_uint(s);
}

__device__ __forceinline__ int key_bin(uint32_t key) {
    // monotone: 16 binades (s in [2^-16, 1)) x 256 mantissa bins; clamped ends.
    int bin = (int)(key >> 15) - 0x6F00;
    bin = bin < 0 ? 0 : bin;
    return bin > 4095 ? 4095 : bin;
}

// ---- pass 1: partial histograms + per-element bin cache (u16) ----------------------
__global__ void k_hist(const float* __restrict__ pred, const float* __restrict__ pmask,
                       uint32_t* __restrict__ histp, ushort* __restrict__ bins) {
    int b = blockIdx.y;
    __shared__ uint32_t lh[NBINS];
    for (int j = threadIdx.x; j < NBINS; j += 256) lh[j] = 0;
    __syncthreads();
    size_t base = (size_t)b * N + blockIdx.x * ELB;
    const float* p = pred + base;
    const float* m = pmask + base;
    ushort* bb = bins + base;
    for (int it = 0; it < (ELB + 1023) / 1024; ++it) {
        int rel = it * 1024 + threadIdx.x * 4;
        if (rel < ELB) {
            float4 pv = *reinterpret_cast<const float4*>(p + rel);
            float4 mv = *reinterpret_cast<const float4*>(m + rel);
            int b0 = key_bin(score_key(pv.x, mv.x));
            int b1 = key_bin(score_key(pv.y, mv.y));
            int b2 = key_bin(score_key(pv.z, mv.z));
            int b3 = key_bin(score_key(pv.w, mv.w));
            atomicAdd(&lh[b0], 1u);
            atomicAdd(&lh[b1], 1u);
            atomicAdd(&lh[b2], 1u);
            atomicAdd(&lh[b3], 1u);
            *reinterpret_cast<ushort4*>(bb + rel) =
                make_ushort4((ushort)b0, (ushort)b1, (ushort)b2, (ushort)b3);
        }
    }
    __syncthreads();
    uint32_t* gh = histp + ((size_t)b * HBLK + blockIdx.x) * NBINS;
    for (int j = threadIdx.x; j < NBINS; j += 256) gh[j] = lh[j];
}

// ---- pass 2: threshold bin Tb + residual rank R, parallel suffix-scan pick ---------
__global__ void k_pick(const uint32_t* __restrict__ histp, int* __restrict__ Tb,
                       int* __restrict__ Rr, uint32_t* __restrict__ poolCnt) {
    int b = blockIdx.x, t = threadIdx.x;
    __shared__ uint32_t lh[NBINS];
    __shared__ uint32_t sc[256];
    __shared__ int s_chunk, s_want2;
    const uint32_t* hb = histp + (size_t)b * HBLK * NBINS;
    uint32_t psum = 0;
    for (int jj = 0; jj < 16; ++jj) {
        int j = t * 16 + jj;
        uint32_t s = 0;
        #pragma unroll
        for (int blk = 0; blk < HBLK; ++blk) s += hb[blk * NBINS + j];
        lh[j] = s;
        psum += s;
    }
    sc[255 - t] = psum;                 // reversed for suffix scan
    __syncthreads();
    for (int off = 1; off < 256; off <<= 1) {
        uint32_t x = sc[t];
        uint32_t y = (t >= off) ? sc[t - off] : 0;
        __syncthreads();
        sc[t] = x + y;
        __syncthreads();
    }
    // S(c) = sum over chunks >= c = sc[255-c]
    int want = NANCH;
    uint32_t Sc  = sc[255 - t];
    uint32_t Sc1 = (t == 255) ? 0u : sc[254 - t];
    if ((int)Sc >= want && (int)Sc1 < want) { s_chunk = t; s_want2 = want - (int)Sc1; }
    __syncthreads();
    if (t == 0) {
        int chunk = s_chunk, want2 = s_want2, acc = 0, bin;
        for (bin = chunk * 16 + 15; bin > chunk * 16; --bin) {
            int c = (int)lh[bin];
            if (acc + c >= want2) break;
            acc += c;
        }
        Tb[b] = bin;
        Rr[b] = want2 - acc;            // #elems to take from the ==Tb pool, >= 1
        poolCnt[b] = 0;                 // zero for k_compact (no memset dispatch)
    }
}

// ---- pass 3: bins -> anchor bit words; boundary pool (key recomputed, rare) --------
__global__ void k_compact(const ushort* __restrict__ bins, const float* __restrict__ pred,
                          const float* __restrict__ pmask, const int* __restrict__ Tb,
                          uint32_t* __restrict__ bits, uint64_t* __restrict__ pool,
                          uint32_t* __restrict__ poolCnt) {
    int b = blockIdx.y;
    int w = blockIdx.x * 256 + threadIdx.x;
    if (w >= NWORDS) return;
    int tb = Tb[b];
    int y = w / WPR, k = w - y * WPR;
    int nv = (k == 12) ? 16 : 32;
    int i0 = y * W + k * 32;
    const ushort* bb = bins + (size_t)b * N + i0;
    uint32_t word = 0;
    for (int j = 0; j < nv; j += 8) {
        uint4 pk = *reinterpret_cast<const uint4*>(bb + j);   // 8 bins
        uint32_t u[4] = {pk.x, pk.y, pk.z, pk.w};
        #pragma unroll
        for (int q = 0; q < 4; ++q) {
            #pragma unroll
            for (int hلف = 0; hلف < 2; ++hلف) {
                int jj = j + 2 * q + hلف;
                int bn = (int)((u[q] >> (16 * hلف)) & 0xFFFFu);
                if (bn > tb) {
                    word |= (1u << jj);
                } else if (bn == tb) {
                    int i = i0 + jj;
                    uint32_t key = score_key(pred[(size_t)b * N + i],
                                             pmask[(size_t)b * N + i]);
                    uint32_t pos = atomicAdd(&poolCnt[b], 1u);
                    if (pos < POOLCAP)
                        pool[(size_t)b * POOLCAP + pos] =
                            ((uint64_t)key << 32) | (uint32_t)(~(uint32_t)i);
                }
            }
        }
    }
    bits[(size_t)b * NWORDS + w] = word;
}

// ---- pass 4: exact radix select, parallel suffix-scan digit pick -------------------
__global__ void k_pool(const uint64_t* __restrict__ pool, const uint32_t* __restrict__ poolCnt,
                       const int* __restrict__ Rr, uint32_t* __restrict__ bits) {
    int b = blockIdx.x, t = threadIdx.x;
    int n = min((int)poolCnt[b], POOLCAP);
    if (n == 0) return;
    const uint64_t* pl = pool + (size_t)b * POOLCAP;
    __shared__ uint32_t h[256];
    __shared__ uint32_t sc[256];
    __shared__ uint64_t s_prefix;
    __shared__ int s_R;
    if (t == 0) { s_prefix = 0; s_R = Rr[b]; }
    __syncthreads();
    for (int d = 7; d >= 0; --d) {
        int shf = d * 8;
        h[t] = 0;
        __syncthreads();                              // B1
        uint64_t pref = s_prefix;
        uint64_t hiMask = (d == 7) ? 0ull : (~0ull << (shf + 8));
        for (int i = t; i < n; i += 256) {
            uint64_t v = pl[i];
            if ((v & hiMask) == pref)
                atomicAdd(&h[(uint32_t)(v >> shf) & 255u], 1u);
        }
        __syncthreads();                              // B2
        sc[255 - t] = h[t];                           // reversed for suffix sums
        __syncthreads();
        for (int off = 1; off < 256; off <<= 1) {
            uint32_t x = sc[t];
            uint32_t y = (t >= off) ? sc[t - off] : 0;
            __syncthreads();
            sc[t] = x + y;
            __syncthreads();
        }
        // S(v) = count of matching entries with digit >= v = sc[255-v]
        uint32_t Sv  = sc[255 - t];
        uint32_t Sv1 = (t == 255) ? 0u : sc[254 - t];
        int R = s_R;
        __syncthreads();                              // B3: all reads of s_R done
        if ((int)Sv >= R && (int)Sv1 < R) {           // exactly one digit wins
            s_R = R - (int)Sv1;
            s_prefix = pref | ((uint64_t)(uint32_t)t << shf);
        }
        __syncthreads();                              // B4
    }
    uint64_t vR = s_prefix;   // exact value of R-th largest (values unique via ~idx)
    for (int i = t; i < n; i += 256) {
        uint64_t v = pl[i];
        if (v >= vR) {
            uint32_t idx = ~((uint32_t)(v & 0xFFFFFFFFull));
            int y = idx / W, x = idx - y * W;
            atomicOr(&bits[(size_t)b * NWORDS + y * WPR + (x >> 5)], 1u << (x & 31));
        }
    }
}

// ---- pass 5: fused 5x5 dilation on bit words + raw block popc sums -----------------
__global__ void k_dil(const uint32_t* __restrict__ src, uint32_t* __restrict__ dst,
                      int* __restrict__ bsum) {
    int b = blockIdx.y, t = threadIdx.x;
    int w = blockIdx.x * 256 + t;
    uint32_t acc = 0;
    if (w < NWORDS) {
        int y = w / WPR, k = w - y * WPR;
        const uint32_t* s = src + (size_t)b * NWORDS;
        int y0 = max(y - 2, 0), y1 = min(y + 2, H - 1);
        for (int yy = y0; yy <= y1; ++yy) {
            const uint32_t* row = s + yy * WPR;
            uint32_t c = row[k];
            uint32_t l = (k > 0) ? row[k - 1] : 0u;
            uint32_t r = (k < 12) ? row[k + 1] : 0u;
            acc |= c | (c << 1) | (c << 2) | (c >> 1) | (c >> 2)
                 | (l >> 30) | (l >> 31) | (r << 30) | (r << 31);
        }
        if (k == 12) acc &= 0xFFFFu;   // row has 400 valid bits
        dst[(size_t)b * NWORDS + w] = acc;
    }
    __shared__ int sh[256];
    sh[t] = __popc(acc);
    __syncthreads();
    for (int off = 128; off > 0; off >>= 1) {
        if (t < off) sh[t] += sh[t + off];
        __syncthreads();
    }
    if (t == 0) bsum[b * NBW + blockIdx.x] = sh[0];
}

// ---- pass 6: ALL outputs, LDS-staged coalesced flush (qpos/xy fused in) ------------
__global__ void k_write(const uint32_t* __restrict__ bits, const int* __restrict__ bsum,
                        const float* __restrict__ zs, float* __restrict__ out) {
    int b = blockIdx.y, blk = blockIdx.x, t = threadIdx.x;
    int w = blk * 256 + t;
    uint32_t word = 0;
    int nv = 0, i0 = 0;
    if (w < NWORDS) {
        int y = w / WPR, k = w - y * WPR;
        nv = (k == 12) ? 16 : 32;
        i0 = y * W + k * 32;
        word = bits[(size_t)b * NWORDS + w];
    }
    __shared__ int bs[32];
    if (t < NBW) bs[t] = bsum[b * NBW + t];
    int cnt = __popc(word);
    int packed = (nv << 16) | cnt;
    __shared__ int sh[256];
    sh[t] = packed;
    __syncthreads();
    for (int off = 1; off < 256; off <<= 1) {
        int x = sh[t];
        int yv = (t >= off) ? sh[t - off] : 0;
        __syncthreads();
        sh[t] = x + yv;
        __syncthreads();
    }
    int exc = sh[t] - packed;
    int truOff = exc & 0xFFFF;          // trues before me in block
    int pixOff = exc >> 16;             // pixels before me in block
    int total = sh[255];
    int blockTrues = total & 0xFFFF;
    int foff = pixOff - truOff;         // falses before me in block
    int blockPix = total >> 16;

    int trBase = 0, T = 0;              // trues before this block / total trues
    for (int j = 0; j < NBW; ++j) {
        int v = bs[j];
        T += v;
        if (j < blk) trBase += v;
    }

    __shared__ uint32_t seg[8192];      // [0,blockTrues): true idxs; rest: false idxs
    {
        int c = truOff, f = blockTrues + foff;
        for (int j = 0; j < nv; ++j) {
            uint32_t i = (uint32_t)(i0 + j);
            if ((word >> j) & 1u) seg[SW(c)] = i, ++c;
            else                  seg[SW(f)] = i, ++f;
        }
    }
    // new_mask: 1 iff orderPos < NPTS (reference scatters out_idx, not dilated mask)
    if (w < NWORDS) {
        float* nm = out + O_NMASK + (size_t)b * N + i0;
        int rk = trBase + truOff;       // global true-rank of my next true pixel
        for (int j = 0; j < nv; j += 4) {
            float4 v;
            float* vv = &v.x;
            #pragma unroll
            for (int q = 0; q < 4; ++q) {
                int i = i0 + j + q;
                int isT = (int)((word >> (j + q)) & 1u);
                int op = isT ? rk : (T + i - rk);
                vv[q] = (op < NPTS) ? 1.0f : 0.0f;
                rk += isT;
            }
            *reinterpret_cast<float4*>(nm + j) = v;
        }
    }
    __syncthreads();
    // coalesced flush of the stable partition + qpos/xy in the same pass
    int w0 = blk * 256;
    int pixBefore = (w0 / WPR) * W + (w0 % WPR) * 32;
    int fBaseG = pixBefore - trBase;    // falses before this block, globally
    float z0 = zs[0], z1 = zs[1], z2 = zs[2], z3 = zs[3];
    float* outIdx = out + (size_t)b * NPTS;
    float* qpos   = out + O_QPOS + (size_t)b * 240000;
    float* xy     = out + O_XY   + (size_t)b * NPTS * 2;
    float* ign    = out + O_IGN  + (size_t)b * (N - NPTS);
    for (int j = t; j < blockPix; j += 256) {
        uint32_t i = seg[SW(j)];
        int op = (j < blockTrues) ? (trBase + j) : (T + fBaseG + (j - blockTrues));
        if (op < NPTS) {
            outIdx[op] = (float)i;
            int yy = (int)i / W, xx = (int)i - yy * W;
            // xy_vox_idx = {i // H, i % W} = {yy, xx}  (H == W == 400)
            *reinterpret_cast<float2*>(xy + 2 * op) =
                make_float2((float)yy, (float)xx);
            float gx = ((float)xx + 0.5f) * 0.0025f;
            float gy = ((float)yy + 0.5f) * 0.0025f;
            float* q = qpos + (size_t)op * 3;
            q[0] = gx; q[1] = gy; q[2] = z0;
            q += 60000; q[0] = gx; q[1] = gy; q[2] = z1;
            q += 60000; q[0] = gx; q[1] = gy; q[2] = z2;
            q += 60000; q[0] = gx; q[1] = gy; q[2] = z3;
        } else {
            ign[op - NPTS] = (float)i;
        }
    }
}

extern "C" void kernel_launch(void* const* d_in, const int* in_sizes, int n_in,
                              void* d_out, int out_size, void* d_ws, size_t ws_size,
                              hipStream_t stream) {
    const float* pred  = (const float*)d_in[0];
    const float* pmask = (const float*)d_in[1];
    const float* zs    = (const float*)d_in[3];
    float* out = (float*)d_out;

    char* ws = (char*)d_ws;
    uint32_t* histp   = (uint32_t*)ws;                          //  8,388,608 B
    uint64_t* pool    = (uint64_t*)(ws + 8388608);              // 16,777,216 B
    uint32_t* abits   = (uint32_t*)(ws + 25165824);             //  2,662,400 B
    uint32_t* dbits   = (uint32_t*)(ws + 27828224);             //  2,662,400 B
    int*      bsum    = (int*)(ws + 30490624);                  //     10,752 B
    int*      Tb      = (int*)(ws + 30501376);
    int*      Rr      = (int*)(ws + 30501888);
    uint32_t* poolCnt = (uint32_t*)(ws + 30502400);
    ushort*   bins    = (ushort*)(ws + 30502912);               // 40,960,000 B

    k_hist<<<dim3(HBLK, B), 256, 0, stream>>>(pred, pmask, histp, bins);
    k_pick<<<B, 256, 0, stream>>>(histp, Tb, Rr, poolCnt);
    dim3 gw(NBW, B);   // 21 x 128
    k_compact<<<gw, 256, 0, stream>>>(bins, pred, pmask, Tb, abits, pool, poolCnt);
    k_pool<<<B, 256, 0, stream>>>(pool, poolCnt, Rr, abits);
    k_dil<<<gw, 256, 0, stream>>>(abits, dbits, bsum);
    k_write<<<gw, 256, 0, stream>>>(dbits, bsum, zs, out);
}